// Round 1
// baseline (733.050 us; speedup 1.0000x reference)
//
#include <hip/hip_runtime.h>
#include <math.h>

#define H 4096       // hidden
#define E 64         // experts
#define BM 32        // rows per block
#define BK 64        // k-window
#define LSTR (BK + 4)  // 68 floats: 272B row stride, 16B aligned, bank-friendly
#define NTHREADS 256

// Block: 256 threads = 4 waves. tx = t&15 (expert group: experts tx+16j),
// ty = t>>4 in 0..15 (rows ty, ty+16). Output tile 32x64.
// LDS double-buffered; register prefetch of next global tile during compute.
__global__ __launch_bounds__(NTHREADS) void router_kernel(
    const float* __restrict__ x, const float* __restrict__ w,
    float* __restrict__ out, int M)
{
    __shared__ __align__(16) float xs[2][BM][LSTR];
    __shared__ __align__(16) float ws[2][E][LSTR];

    const int t  = threadIdx.x;
    const int tx = t & 15;
    const int ty = t >> 4;
    const int m0 = blockIdx.x * BM;

    float* logits   = out;
    float* idx_out  = out + (size_t)M * E;
    float* prob_out = idx_out + (size_t)M * 2;

    // staging mapping: flat float4 index f = t + 256*p; row = f>>4, c4 = f&15
    const int srow = t >> 4;   // 0..15
    const int sc4  = t & 15;   // float4 column within 64-float row chunk

    float4 xr[2], wr[4];

    auto load_tile = [&](int k0) {
        const float* xp = x + (size_t)(m0 + srow) * H + k0 + (sc4 << 2);
        xr[0] = *(const float4*)xp;
        xr[1] = *(const float4*)(xp + (size_t)16 * H);
        const float* wp = w + (size_t)srow * H + k0 + (sc4 << 2);
#pragma unroll
        for (int p = 0; p < 4; ++p)
            wr[p] = *(const float4*)(wp + (size_t)16 * p * H);
    };

    auto store_tile = [&](int b) {
        *(float4*)&xs[b][srow][sc4 << 2]      = xr[0];
        *(float4*)&xs[b][srow + 16][sc4 << 2] = xr[1];
#pragma unroll
        for (int p = 0; p < 4; ++p)
            *(float4*)&ws[b][srow + 16 * p][sc4 << 2] = wr[p];
    };

    float acc[2][4];
#pragma unroll
    for (int i = 0; i < 2; ++i)
#pragma unroll
        for (int j = 0; j < 4; ++j) acc[i][j] = 0.0f;

    load_tile(0);
    store_tile(0);
    __syncthreads();

    const int nwin = H / BK;   // 64
    for (int win = 0; win < nwin; ++win) {
        const int buf = win & 1;
        if (win + 1 < nwin) load_tile((win + 1) * BK);

#pragma unroll
        for (int k4 = 0; k4 < BK / 4; ++k4) {
            float4 xf0 = *(const float4*)&xs[buf][ty][k4 << 2];
            float4 xf1 = *(const float4*)&xs[buf][ty + 16][k4 << 2];
            float4 wf[4];
#pragma unroll
            for (int j = 0; j < 4; ++j)
                wf[j] = *(const float4*)&ws[buf][tx + 16 * j][k4 << 2];
#pragma unroll
            for (int j = 0; j < 4; ++j) {
                acc[0][j] += xf0.x * wf[j].x;
                acc[0][j] += xf0.y * wf[j].y;
                acc[0][j] += xf0.z * wf[j].z;
                acc[0][j] += xf0.w * wf[j].w;
                acc[1][j] += xf1.x * wf[j].x;
                acc[1][j] += xf1.y * wf[j].y;
                acc[1][j] += xf1.z * wf[j].z;
                acc[1][j] += xf1.w * wf[j].w;
            }
        }

        if (win + 1 < nwin) store_tile(1 - buf);
        __syncthreads();
    }

    // ---- epilogue: write logits (coalesced by tx) ----
#pragma unroll
    for (int i = 0; i < 2; ++i) {
        const int m = m0 + ty + 16 * i;
#pragma unroll
        for (int j = 0; j < 4; ++j)
            logits[(size_t)m * E + tx + 16 * j] = acc[i][j];
    }

    // ---- top-2 over 64 experts per row (16-lane group owns a row) ----
#pragma unroll
    for (int i = 0; i < 2; ++i) {
        float v1 = -INFINITY, v2 = -INFINITY;
        int   i1 = 0x7fffffff, i2 = 0x7fffffff;
#pragma unroll
        for (int j = 0; j < 4; ++j) {       // ascending expert index
            const float v = acc[i][j];
            const int   e = tx + 16 * j;
            if (v > v1)      { v2 = v1; i2 = i1; v1 = v; i1 = e; }
            else if (v > v2) { v2 = v;  i2 = e; }
        }
#pragma unroll
        for (int mask = 1; mask < 16; mask <<= 1) {
            const float ov1 = __shfl_xor(v1, mask);
            const float ov2 = __shfl_xor(v2, mask);
            const int   oi1 = __shfl_xor(i1, mask);
            const int   oi2 = __shfl_xor(i2, mask);
            // merge two sorted top-2 lists; tie -> lower index first
            const bool afirst = (v1 > ov1) || (v1 == ov1 && i1 < oi1);
            float nv1, nv2; int ni1, ni2;
            if (afirst) {
                nv1 = v1; ni1 = i1;
                const bool s = (v2 > ov1) || (v2 == ov1 && i2 < oi1);
                nv2 = s ? v2 : ov1; ni2 = s ? i2 : oi1;
            } else {
                nv1 = ov1; ni1 = oi1;
                const bool s = (ov2 > v1) || (ov2 == v1 && oi2 < i1);
                nv2 = s ? ov2 : v1; ni2 = s ? oi2 : i1;
            }
            v1 = nv1; v2 = nv2; i1 = ni1; i2 = ni2;
        }
        if (tx == 0) {
            const int m = m0 + ty + 16 * i;
            const float e2    = __expf(v2 - v1);   // <= 1
            const float denom = 1.0f + e2;
            idx_out [(size_t)m * 2]     = (float)i1;
            idx_out [(size_t)m * 2 + 1] = (float)i2;
            prob_out[(size_t)m * 2]     = 1.0f / denom;
            prob_out[(size_t)m * 2 + 1] = e2 / denom;
        }
    }
}

extern "C" void kernel_launch(void* const* d_in, const int* in_sizes, int n_in,
                              void* d_out, int out_size, void* d_ws, size_t ws_size,
                              hipStream_t stream) {
    const float* x = (const float*)d_in[0];
    const float* w = (const float*)d_in[1];
    const int M = in_sizes[0] / H;   // 4*4096 = 16384 rows
    dim3 grid(M / BM), block(NTHREADS);
    hipLaunchKernelGGL(router_kernel, grid, block, 0, stream,
                       x, w, (float*)d_out, M);
}